// Round 1
// baseline (3857.109 us; speedup 1.0000x reference)
//
#include <hip/hip_runtime.h>
#include <math.h>

#define S_DIM 8
#define SA_DIM 10
#define NN 256

// ---------------- workspace layout (float offsets) ----------------
constexpr size_t OFF_K     = 0;                          // 8*256*256  (K, then L in-place, lower tri)
constexpr size_t OFF_LINV  = OFF_K    + 8ull*NN*NN;      // 8*256*256
constexpr size_t OFF_KINV  = OFF_LINV + 8ull*NN*NN;      // 8*256*256
constexpr size_t OFF_RD    = OFF_KINV + 8ull*NN*NN;      // 8*256 reciprocal diag of L
constexpr size_t OFF_U     = OFF_RD   + 8*NN;            // 8*256*10  u = (x-mean)*inv_scales
constexpr size_t OFF_LK    = OFF_U    + 8*NN*SA_DIM;     // 8*256     log k(mean, x_n)
constexpr size_t OFF_M     = OFF_LK   + 8*NN;            // 64*100    M_ab
constexpr size_t OFF_C     = OFF_M    + 64*100;          // 64        -0.5*logdet R
constexpr size_t OFF_AINV  = OFF_C    + 64;              // 8*100
constexpr size_t OFF_AIM   = OFF_AINV + 800;             // 8*10      Ainv @ mean
constexpr size_t OFF_MDC   = OFF_AIM  + 80;              // 8         mean det coeff
constexpr size_t OFF_BETA  = OFF_MDC  + 8;               // 8*256
constexpr size_t OFF_MEAN  = OFF_BETA + 8*NN;            // 8
constexpr size_t OFF_CROSS = OFF_MEAN + 8;               // 80  cross_cov[d][g]
constexpr size_t OFF_COVP  = OFF_CROSS+ 80;              // 256 partials
constexpr size_t OFF_TRP   = OFF_COVP + 256;             // 32  trace partials

// ---------------- K0: build data covariance K[g][n][m] ----------------
__global__ __launch_bounds__(256) void k_build_K(const float* __restrict__ x,
                                                 const float* __restrict__ eqc,
                                                 const float* __restrict__ scales,
                                                 const float* __restrict__ noise,
                                                 float* __restrict__ Kw) {
  int g = blockIdx.x >> 8;
  int n = blockIdx.x & 255;
  int m = threadIdx.x;
  __shared__ float xs[NN * SA_DIM];
  __shared__ float isc[SA_DIM];
  for (int i = threadIdx.x; i < NN * SA_DIM; i += 256) xs[i] = x[i];
  if (threadIdx.x < SA_DIM) isc[threadIdx.x] = 1.0f / scales[g * SA_DIM + threadIdx.x];
  __syncthreads();
  float quad = 0.f;
#pragma unroll
  for (int d = 0; d < SA_DIM; d++) {
    float df = xs[n * SA_DIM + d] - xs[m * SA_DIM + d];
    quad += df * df * isc[d];
  }
  float v = eqc[g] * __expf(-0.5f * quad);
  if (m == n) v += noise[g];
  Kw[(size_t)g * NN * NN + (size_t)n * NN + m] = v;
}

// ---------------- K0b: u = nu*inv_scales, lk = log k(mean, x_n) ----------------
__global__ __launch_bounds__(256) void k_prep(const float* __restrict__ x,
                                              const float* __restrict__ mf,
                                              const float* __restrict__ eqc,
                                              const float* __restrict__ scales,
                                              float* __restrict__ u,
                                              float* __restrict__ lkw) {
  int g = blockIdx.x;
  int n = threadIdx.x;
  float quad = 0.f;
#pragma unroll
  for (int d = 0; d < SA_DIM; d++) {
    float isc = 1.0f / scales[g * SA_DIM + d];
    float nu = x[n * SA_DIM + d] - mf[d];
    u[((size_t)g * NN + n) * SA_DIM + d] = nu * isc;
    quad += nu * nu * isc;
  }
  lkw[g * NN + n] = logf(eqc[g]) - 0.5f * quad;
}

// ---------------- Gauss-Jordan inverse, 10x10, no pivoting (matrices are I+PSD-like) ----
__device__ void gj_invert10(float A[SA_DIM][SA_DIM], float B[SA_DIM][SA_DIM], float* logdet) {
#pragma unroll
  for (int i = 0; i < SA_DIM; i++)
#pragma unroll
    for (int j = 0; j < SA_DIM; j++) B[i][j] = (i == j) ? 1.f : 0.f;
  float ld = 0.f;
#pragma unroll
  for (int k = 0; k < SA_DIM; k++) {
    float pv = A[k][k];
    ld += logf(pv);
    float ip = 1.f / pv;
#pragma unroll
    for (int j = 0; j < SA_DIM; j++) { A[k][j] *= ip; B[k][j] *= ip; }
#pragma unroll
    for (int r = 0; r < SA_DIM; r++) {
      if (r == k) continue;
      float f = A[r][k];
#pragma unroll
      for (int j = 0; j < SA_DIM; j++) { A[r][j] -= f * A[k][j]; B[r][j] -= f * B[k][j]; }
    }
  }
  *logdet = ld;
}

// ---------------- K-small: per-pair R^-1, M_ab, c_ab; per-g Ainv, aim, mdc ----------------
__global__ __launch_bounds__(64) void k_small(const float* __restrict__ cov,
                                              const float* __restrict__ scales,
                                              const float* __restrict__ eqc,
                                              const float* __restrict__ mf,
                                              float* __restrict__ Mw, float* __restrict__ cvec,
                                              float* __restrict__ Ainvw, float* __restrict__ aimw,
                                              float* __restrict__ mdcw) {
  int p = threadIdx.x;
  if (p >= 64) return;
  int a = p >> 3, b = p & 7;
  float A[SA_DIM][SA_DIM], B[SA_DIM][SA_DIM];
  for (int i = 0; i < SA_DIM; i++)
    for (int j = 0; j < SA_DIM; j++)
      A[i][j] = cov[i * SA_DIM + j] * (1.f / scales[a * SA_DIM + j] + 1.f / scales[b * SA_DIM + j]) +
                ((i == j) ? 1.f : 0.f);
  float ld;
  gj_invert10(A, B, &ld);
  cvec[p] = -0.5f * ld;
  for (int i = 0; i < SA_DIM; i++)
    for (int j = 0; j < SA_DIM; j++) {
      float v = 0.f;
      for (int k = 0; k < SA_DIM; k++) v += B[i][k] * cov[k * SA_DIM + j];
      Mw[p * 100 + i * SA_DIM + j] = v;
    }
  if (b == 0) {
    int g = a;
    // Ainv of cov + diag(scales_g)
    for (int i = 0; i < SA_DIM; i++)
      for (int j = 0; j < SA_DIM; j++)
        A[i][j] = cov[i * SA_DIM + j] + ((i == j) ? scales[g * SA_DIM + j] : 0.f);
    float ld2;
    gj_invert10(A, B, &ld2);
    for (int i = 0; i < SA_DIM; i++)
      for (int j = 0; j < SA_DIM; j++) Ainvw[g * 100 + i * SA_DIM + j] = B[i][j];
    for (int i = 0; i < SA_DIM; i++) {
      float v = 0.f;
      for (int j = 0; j < SA_DIM; j++) v += B[i][j] * mf[j];
      aimw[g * SA_DIM + i] = v;
    }
    // det of cov*diag(1/scales_g) + I
    for (int i = 0; i < SA_DIM; i++)
      for (int j = 0; j < SA_DIM; j++)
        A[i][j] = cov[i * SA_DIM + j] * (1.f / scales[g * SA_DIM + j]) + ((i == j) ? 1.f : 0.f);
    float ld3;
    gj_invert10(A, B, &ld3);
    mdcw[g] = eqc[g] * __expf(-0.5f * ld3);
  }
}

// ---------------- K1: Cholesky, one block per g, in-place lower triangle ----------------
__global__ __launch_bounds__(256) void k_chol(float* __restrict__ Kw, float* __restrict__ rd) {
  float* A = Kw + (size_t)blockIdx.x * NN * NN;
  float* rdg = rd + blockIdx.x * NN;
  int t = threadIdx.x;
  __shared__ float col[NN];
  __shared__ float dsh;  // reciprocal of diag
  for (int k = 0; k < NN; k++) {
    if (t == 0) {
      float dv = sqrtf(A[k * NN + k]);
      A[k * NN + k] = dv;
      float r = 1.f / dv;
      rdg[k] = r;
      dsh = r;
    }
    __syncthreads();
    float lj = 0.f;
    if (t > k) {
      lj = A[t * NN + k] * dsh;
      A[t * NN + k] = lj;
    }
    col[t] = lj;
    __syncthreads();
    if (t > k) {
      float ljk = col[t];
      float* Arow = A + (size_t)t * NN;
      for (int i = k + 1; i <= t; i++) Arow[i] -= ljk * col[i];
    }
    __syncthreads();
  }
}

// ---------------- K2: Linv, one wave per column (forward substitution) ----------------
__global__ __launch_bounds__(256) void k_linv(const float* __restrict__ L,
                                              const float* __restrict__ rd,
                                              float* __restrict__ Linv) {
  int gw = (blockIdx.x * 256 + threadIdx.x) >> 6;  // global wave id, 2048 total
  int lane = threadIdx.x & 63;
  int g = gw >> 8;
  int j = gw & 255;
  const float* Lg = L + (size_t)g * NN * NN;
  float* Og = Linv + (size_t)g * NN * NN;
  const float* rdg = rd + g * NN;
  float b0 = (lane == j) ? 1.f : 0.f;
  float b1 = (lane + 64 == j) ? 1.f : 0.f;
  float b2 = (lane + 128 == j) ? 1.f : 0.f;
  float b3 = (lane + 192 == j) ? 1.f : 0.f;
  // zero the strictly-upper part of this column
#pragma unroll
  for (int q = 0; q < 4; q++) {
    int i = lane + 64 * q;
    if (i < j) Og[(size_t)i * NN + j] = 0.f;
  }
  for (int k = j; k < NN; k++) {
    int src = k & 63;
    int reg = k >> 6;
    float bk;
    if (reg == 0) bk = __shfl(b0, src);
    else if (reg == 1) bk = __shfl(b1, src);
    else if (reg == 2) bk = __shfl(b2, src);
    else bk = __shfl(b3, src);
    float xk = bk * rdg[k];
    if (lane == 0) Og[(size_t)k * NN + j] = xk;
    int i0 = lane, i1 = lane + 64, i2 = lane + 128, i3 = lane + 192;
    if (i0 > k) b0 -= Lg[(size_t)i0 * NN + k] * xk;
    if (i1 > k) b1 -= Lg[(size_t)i1 * NN + k] * xk;
    if (i2 > k) b2 -= Lg[(size_t)i2 * NN + k] * xk;
    if (i3 > k) b3 -= Lg[(size_t)i3 * NN + k] * xk;
  }
}

// ---------------- K3: Kinv = Linv^T Linv (tiled SYRK-as-GEMM) ----------------
__global__ __launch_bounds__(256) void k_syrk(const float* __restrict__ Linv,
                                              float* __restrict__ Kinv) {
  int g = blockIdx.x >> 4;
  int tile = blockIdx.x & 15;
  int i0 = (tile >> 2) * 64, j0 = (tile & 3) * 64;
  const float* A = Linv + (size_t)g * NN * NN;
  float* O = Kinv + (size_t)g * NN * NN;
  __shared__ float sa[32][64], sb[32][64];
  int tx = threadIdx.x & 15, ty = threadIdx.x >> 4;
  float acc[4][4] = {{0.f}};
  for (int k0 = 0; k0 < NN; k0 += 32) {
    for (int e = threadIdx.x; e < 2048; e += 256) {
      int kk = e >> 6, cc = e & 63;
      sa[kk][cc] = A[(size_t)(k0 + kk) * NN + i0 + cc];
      sb[kk][cc] = A[(size_t)(k0 + kk) * NN + j0 + cc];
    }
    __syncthreads();
#pragma unroll 8
    for (int kk = 0; kk < 32; kk++) {
      float av[4], bv[4];
#pragma unroll
      for (int q = 0; q < 4; q++) { av[q] = sa[kk][ty * 4 + q]; bv[q] = sb[kk][tx * 4 + q]; }
#pragma unroll
      for (int q = 0; q < 4; q++)
#pragma unroll
        for (int r = 0; r < 4; r++) acc[q][r] += av[q] * bv[r];
    }
    __syncthreads();
  }
#pragma unroll
  for (int q = 0; q < 4; q++)
#pragma unroll
    for (int r = 0; r < 4; r++)
      O[(size_t)(i0 + ty * 4 + q) * NN + j0 + tx * 4 + r] = acc[q][r];
}

// ---------------- K3b: beta = Kinv @ y ----------------
__global__ __launch_bounds__(256) void k_beta(const float* __restrict__ Kinv,
                                              const float* __restrict__ y,
                                              float* __restrict__ betaw) {
  int g = blockIdx.x, n = threadIdx.x;
  __shared__ float ys[NN];
  ys[n] = y[n * S_DIM + g];
  __syncthreads();
  const float* Kg = Kinv + (size_t)g * NN * NN + (size_t)n * NN;
  float acc = 0.f;
  for (int m = 0; m < NN; m++) acc += Kg[m] * ys[m];
  betaw[g * NN + n] = acc;
}

// ---------------- K6: the big fused Q reduction ----------------
__global__ __launch_bounds__(256) void k_qsum(const float* __restrict__ u,
                                              const float* __restrict__ lkw,
                                              const float* __restrict__ Mw,
                                              const float* __restrict__ cvec,
                                              const float* __restrict__ betaw,
                                              const float* __restrict__ Kinv,
                                              float* __restrict__ covp, float* __restrict__ trp) {
  int p = blockIdx.x >> 2;
  int quarter = blockIdx.x & 3;
  int a = p >> 3, b = p & 7;
  int t = threadIdx.x;
  __shared__ float ub[NN * SA_DIM];
  __shared__ float Ms[100];
  __shared__ float sbv[NN];
  __shared__ float eb[NN];
  __shared__ float red[256];
  for (int idx = t; idx < NN * SA_DIM; idx += 256) ub[idx] = u[(size_t)b * NN * SA_DIM + idx];
  if (t < 100) Ms[t] = Mw[p * 100 + t];
  __syncthreads();
  {
    int m = t;
    float q = 0.f;
#pragma unroll
    for (int d = 0; d < SA_DIM; d++) {
      float v = 0.f;
#pragma unroll
      for (int e = 0; e < SA_DIM; e++) v += Ms[d * SA_DIM + e] * ub[m * SA_DIM + e];
      q += v * ub[m * SA_DIM + d];
    }
    sbv[m] = lkw[b * NN + m] + 0.5f * q;
    eb[m] = betaw[b * NN + m];
  }
  __syncthreads();
  int n = quarter * 64 + (t >> 2);
  int c = t & 3;
  float ua[SA_DIM];
#pragma unroll
  for (int d = 0; d < SA_DIM; d++) ua[d] = u[((size_t)a * NN + n) * SA_DIM + d];
  float va[SA_DIM];
#pragma unroll
  for (int d = 0; d < SA_DIM; d++) {
    float v = 0.f;
#pragma unroll
    for (int e = 0; e < SA_DIM; e++) v += Ms[d * SA_DIM + e] * ua[e];
    va[d] = v;
  }
  float qa = 0.f;
#pragma unroll
  for (int d = 0; d < SA_DIM; d++) qa += va[d] * ua[d];
  float pa = lkw[a * NN + n] + 0.5f * qa + cvec[p];
  float wa = betaw[a * NN + n];
  const float* Krow = Kinv + (size_t)a * NN * NN + (size_t)n * NN;
  float covacc = 0.f, tracc = 0.f;
  bool dg = (a == b);
  for (int ii = 0; ii < 64; ii++) {
    int mm = c + 4 * ii;
    float s = pa + sbv[mm];
#pragma unroll
    for (int d = 0; d < SA_DIM; d++) s += va[d] * ub[mm * SA_DIM + d];
    float e = __expf(s);
    covacc += eb[mm] * e;
    if (dg) tracc += Krow[mm] * e;
  }
  covacc *= wa;
  red[t] = covacc;
  __syncthreads();
  for (int st = 128; st > 0; st >>= 1) {
    if (t < st) red[t] += red[t + st];
    __syncthreads();
  }
  if (t == 0) covp[blockIdx.x] = red[0];
  if (dg) {
    red[t] = tracc;
    __syncthreads();
    for (int st = 128; st > 0; st >>= 1) {
      if (t < st) red[t] += red[t + st];
      __syncthreads();
    }
    if (t == 0) trp[a * 4 + quarter] = red[0];
  }
}

// ---------------- K7: mean + cross-cov reductions ----------------
__global__ __launch_bounds__(256) void k_meancross(const float* __restrict__ x,
                                                   const float* __restrict__ mf,
                                                   const float* __restrict__ cov,
                                                   const float* __restrict__ scales,
                                                   const float* __restrict__ Ainvw,
                                                   const float* __restrict__ aimw,
                                                   const float* __restrict__ mdcw,
                                                   const float* __restrict__ betaw,
                                                   float* __restrict__ meanw,
                                                   float* __restrict__ crossw) {
  int g = blockIdx.x;
  int i = threadIdx.x;
  __shared__ float Ai[100], cv[100], aims[SA_DIM], sc[SA_DIM], mfs[SA_DIM];
  __shared__ float red[256];
  if (i < 100) { Ai[i] = Ainvw[g * 100 + i]; cv[i] = cov[i]; }
  if (i < SA_DIM) { aims[i] = aimw[g * SA_DIM + i]; sc[i] = scales[g * SA_DIM + i]; mfs[i] = mf[i]; }
  __syncthreads();
  float xi[SA_DIM], nu[SA_DIM];
#pragma unroll
  for (int d = 0; d < SA_DIM; d++) { xi[d] = x[i * SA_DIM + d]; nu[d] = xi[d] - mfs[d]; }
  float sv[SA_DIM], ad[SA_DIM];
#pragma unroll
  for (int d = 0; d < SA_DIM; d++) {
    float s1 = 0.f, s2 = 0.f;
#pragma unroll
    for (int e = 0; e < SA_DIM; e++) { s1 += Ai[d * SA_DIM + e] * nu[e]; s2 += Ai[d * SA_DIM + e] * xi[e]; }
    sv[d] = s1;
    ad[d] = s2;
  }
  float mq = 0.f;
#pragma unroll
  for (int d = 0; d < SA_DIM; d++) mq += nu[d] * sv[d];
  float bg = betaw[g * NN + i];
  float mexp = mdcw[g] * __expf(-0.5f * mq);
  float cm = bg * mexp;
  float contrib[SA_DIM];
#pragma unroll
  for (int d = 0; d < SA_DIM; d++) {
    float ccm = sc[d] * aims[d];
#pragma unroll
    for (int j = 0; j < SA_DIM; j++) ccm += cv[d * SA_DIM + j] * ad[j];
    contrib[d] = mexp * ccm * bg;
  }
  red[i] = cm;
  __syncthreads();
  for (int st = 128; st > 0; st >>= 1) {
    if (i < st) red[i] += red[i + st];
    __syncthreads();
  }
  if (i == 0) meanw[g] = red[0];
  for (int d = 0; d < SA_DIM; d++) {
    __syncthreads();
    red[i] = contrib[d];
    __syncthreads();
    for (int st = 128; st > 0; st >>= 1) {
      if (i < st) red[i] += red[i + st];
      __syncthreads();
    }
    if (i == 0) crossw[d * S_DIM + g] = red[0];
  }
}

// ---------------- K8: final assembly ----------------
__global__ __launch_bounds__(64) void k_final(const float* __restrict__ covp,
                                              const float* __restrict__ trp,
                                              const float* __restrict__ meanw,
                                              const float* __restrict__ crossw,
                                              const float* __restrict__ cov,
                                              const float* __restrict__ eqc,
                                              const float* __restrict__ mf,
                                              float* __restrict__ out) {
  int p = threadIdx.x;
  if (p >= 64) return;
  int a = p >> 3, b = p & 7;
  float covq = covp[p * 4] + covp[p * 4 + 1] + covp[p * 4 + 2] + covp[p * 4 + 3];
  float ma = meanw[a], mb = meanw[b];
  float val = covq - ma * mb + cov[a * SA_DIM + b];
  if (a == b) {
    float tr = trp[a * 4] + trp[a * 4 + 1] + trp[a * 4 + 2] + trp[a * 4 + 3];
    val += eqc[a] - tr;
  }
  val += (crossw[a * S_DIM + b] - mf[a] * mb) + (crossw[b * S_DIM + a] - mf[b] * ma);
  out[S_DIM + p] = val;
  if (p < S_DIM) out[p] = meanw[p] + mf[p];
}

extern "C" void kernel_launch(void* const* d_in, const int* in_sizes, int n_in,
                              void* d_out, int out_size, void* d_ws, size_t ws_size,
                              hipStream_t stream) {
  const float* mf     = (const float*)d_in[0];  // [10]
  const float* cov    = (const float*)d_in[1];  // [10,10]
  const float* x      = (const float*)d_in[2];  // [256,10]
  const float* y      = (const float*)d_in[3];  // [256,8]
  const float* eqc    = (const float*)d_in[4];  // [8]
  const float* scales = (const float*)d_in[5];  // [8,10]
  const float* noise  = (const float*)d_in[6];  // [8]
  float* ws = (float*)d_ws;

  float* Kw    = ws + OFF_K;
  float* Linv  = ws + OFF_LINV;
  float* Kinv  = ws + OFF_KINV;
  float* rd    = ws + OFF_RD;
  float* u     = ws + OFF_U;
  float* lkw   = ws + OFF_LK;
  float* Mw    = ws + OFF_M;
  float* cvec  = ws + OFF_C;
  float* Ainvw = ws + OFF_AINV;
  float* aimw  = ws + OFF_AIM;
  float* mdcw  = ws + OFF_MDC;
  float* betaw = ws + OFF_BETA;
  float* meanw = ws + OFF_MEAN;
  float* crossw= ws + OFF_CROSS;
  float* covp  = ws + OFF_COVP;
  float* trp   = ws + OFF_TRP;

  k_build_K<<<2048, 256, 0, stream>>>(x, eqc, scales, noise, Kw);
  k_prep<<<8, 256, 0, stream>>>(x, mf, eqc, scales, u, lkw);
  k_small<<<1, 64, 0, stream>>>(cov, scales, eqc, mf, Mw, cvec, Ainvw, aimw, mdcw);
  k_chol<<<8, 256, 0, stream>>>(Kw, rd);
  k_linv<<<512, 256, 0, stream>>>(Kw, rd, Linv);
  k_syrk<<<128, 256, 0, stream>>>(Linv, Kinv);
  k_beta<<<8, 256, 0, stream>>>(Kinv, y, betaw);
  k_qsum<<<256, 256, 0, stream>>>(u, lkw, Mw, cvec, betaw, Kinv, covp, trp);
  k_meancross<<<8, 256, 0, stream>>>(x, mf, cov, scales, Ainvw, aimw, mdcw, betaw, meanw, crossw);
  k_final<<<1, 64, 0, stream>>>(covp, trp, meanw, crossw, cov, eqc, mf, (float*)d_out);
}

// Round 2
// 615.048 us; speedup vs baseline: 6.2712x; 6.2712x over previous
//
#include <hip/hip_runtime.h>
#include <math.h>

#define S_DIM 8
#define SA_DIM 10
#define NN 256

// ---------------- workspace layout (float offsets) ----------------
constexpr size_t OFF_K     = 0;                          // 8*256*256  (K, then LT in-place: LT[k][i] = L[i][k])
constexpr size_t OFF_LINV  = OFF_K    + 8ull*NN*NN;      // 8*256*256
constexpr size_t OFF_KINV  = OFF_LINV + 8ull*NN*NN;      // 8*256*256
constexpr size_t OFF_RD    = OFF_KINV + 8ull*NN*NN;      // 8*256 reciprocal diag of L
constexpr size_t OFF_U     = OFF_RD   + 8*NN;            // 8*256*10  u = (x-mean)*inv_scales
constexpr size_t OFF_LK    = OFF_U    + 8*NN*SA_DIM;     // 8*256     log k(mean, x_n)
constexpr size_t OFF_M     = OFF_LK   + 8*NN;            // 64*100    M_ab
constexpr size_t OFF_C     = OFF_M    + 64*100;          // 64        -0.5*logdet R
constexpr size_t OFF_AINV  = OFF_C    + 64;              // 8*100
constexpr size_t OFF_AIM   = OFF_AINV + 800;             // 8*10      Ainv @ mean
constexpr size_t OFF_MDC   = OFF_AIM  + 80;              // 8         mean det coeff
constexpr size_t OFF_BETA  = OFF_MDC  + 8;               // 8*256
constexpr size_t OFF_MEAN  = OFF_BETA + 8*NN;            // 8
constexpr size_t OFF_CROSS = OFF_MEAN + 8;               // 80  cross_cov[d][g]
constexpr size_t OFF_COVP  = OFF_CROSS+ 80;              // 256 partials
constexpr size_t OFF_TRP   = OFF_COVP + 256;             // 32  trace partials

// ---------------- K0: build data covariance K[g][n][m] ----------------
__global__ __launch_bounds__(256) void k_build_K(const float* __restrict__ x,
                                                 const float* __restrict__ eqc,
                                                 const float* __restrict__ scales,
                                                 const float* __restrict__ noise,
                                                 float* __restrict__ Kw) {
  int g = blockIdx.x >> 8;
  int n = blockIdx.x & 255;
  int m = threadIdx.x;
  __shared__ float xs[NN * SA_DIM];
  __shared__ float isc[SA_DIM];
  for (int i = threadIdx.x; i < NN * SA_DIM; i += 256) xs[i] = x[i];
  if (threadIdx.x < SA_DIM) isc[threadIdx.x] = 1.0f / scales[g * SA_DIM + threadIdx.x];
  __syncthreads();
  float quad = 0.f;
#pragma unroll
  for (int d = 0; d < SA_DIM; d++) {
    float df = xs[n * SA_DIM + d] - xs[m * SA_DIM + d];
    quad += df * df * isc[d];
  }
  float v = eqc[g] * __expf(-0.5f * quad);
  if (m == n) v += noise[g];
  Kw[(size_t)g * NN * NN + (size_t)n * NN + m] = v;
}

// ---------------- K0b: u = nu*inv_scales, lk = log k(mean, x_n) ----------------
__global__ __launch_bounds__(256) void k_prep(const float* __restrict__ x,
                                              const float* __restrict__ mf,
                                              const float* __restrict__ eqc,
                                              const float* __restrict__ scales,
                                              float* __restrict__ u,
                                              float* __restrict__ lkw) {
  int g = blockIdx.x;
  int n = threadIdx.x;
  float quad = 0.f;
#pragma unroll
  for (int d = 0; d < SA_DIM; d++) {
    float isc = 1.0f / scales[g * SA_DIM + d];
    float nu = x[n * SA_DIM + d] - mf[d];
    u[((size_t)g * NN + n) * SA_DIM + d] = nu * isc;
    quad += nu * nu * isc;
  }
  lkw[g * NN + n] = logf(eqc[g]) - 0.5f * quad;
}

// ---------------- Gauss-Jordan inverse, 10x10, no pivoting (matrices are I+PSD-like) ----
__device__ void gj_invert10(float A[SA_DIM][SA_DIM], float B[SA_DIM][SA_DIM], float* logdet) {
#pragma unroll
  for (int i = 0; i < SA_DIM; i++)
#pragma unroll
    for (int j = 0; j < SA_DIM; j++) B[i][j] = (i == j) ? 1.f : 0.f;
  float ld = 0.f;
#pragma unroll
  for (int k = 0; k < SA_DIM; k++) {
    float pv = A[k][k];
    ld += logf(pv);
    float ip = 1.f / pv;
#pragma unroll
    for (int j = 0; j < SA_DIM; j++) { A[k][j] *= ip; B[k][j] *= ip; }
#pragma unroll
    for (int r = 0; r < SA_DIM; r++) {
      if (r == k) continue;
      float f = A[r][k];
#pragma unroll
      for (int j = 0; j < SA_DIM; j++) { A[r][j] -= f * A[k][j]; B[r][j] -= f * B[k][j]; }
    }
  }
  *logdet = ld;
}

// ---------------- K-small: per-pair R^-1, M_ab, c_ab; per-g Ainv, aim, mdc ----------------
__global__ __launch_bounds__(64) void k_small(const float* __restrict__ cov,
                                              const float* __restrict__ scales,
                                              const float* __restrict__ eqc,
                                              const float* __restrict__ mf,
                                              float* __restrict__ Mw, float* __restrict__ cvec,
                                              float* __restrict__ Ainvw, float* __restrict__ aimw,
                                              float* __restrict__ mdcw) {
  int p = threadIdx.x;
  if (p >= 64) return;
  int a = p >> 3, b = p & 7;
  float A[SA_DIM][SA_DIM], B[SA_DIM][SA_DIM];
  for (int i = 0; i < SA_DIM; i++)
    for (int j = 0; j < SA_DIM; j++)
      A[i][j] = cov[i * SA_DIM + j] * (1.f / scales[a * SA_DIM + j] + 1.f / scales[b * SA_DIM + j]) +
                ((i == j) ? 1.f : 0.f);
  float ld;
  gj_invert10(A, B, &ld);
  cvec[p] = -0.5f * ld;
  for (int i = 0; i < SA_DIM; i++)
    for (int j = 0; j < SA_DIM; j++) {
      float v = 0.f;
      for (int k = 0; k < SA_DIM; k++) v += B[i][k] * cov[k * SA_DIM + j];
      Mw[p * 100 + i * SA_DIM + j] = v;
    }
  if (b == 0) {
    int g = a;
    for (int i = 0; i < SA_DIM; i++)
      for (int j = 0; j < SA_DIM; j++)
        A[i][j] = cov[i * SA_DIM + j] + ((i == j) ? scales[g * SA_DIM + j] : 0.f);
    float ld2;
    gj_invert10(A, B, &ld2);
    for (int i = 0; i < SA_DIM; i++)
      for (int j = 0; j < SA_DIM; j++) Ainvw[g * 100 + i * SA_DIM + j] = B[i][j];
    for (int i = 0; i < SA_DIM; i++) {
      float v = 0.f;
      for (int j = 0; j < SA_DIM; j++) v += B[i][j] * mf[j];
      aimw[g * SA_DIM + i] = v;
    }
    for (int i = 0; i < SA_DIM; i++)
      for (int j = 0; j < SA_DIM; j++)
        A[i][j] = cov[i * SA_DIM + j] * (1.f / scales[g * SA_DIM + j]) + ((i == j) ? 1.f : 0.f);
    float ld3;
    gj_invert10(A, B, &ld3);
    mdcw[g] = eqc[g] * __expf(-0.5f * ld3);
  }
}

// ---------------- K1: column-register Cholesky, one block (1024 thr) per g ----------------
// Wave w owns columns j = cI*16 + w (cI=0..15); lane holds rows [4*lane, 4*lane+4) of each
// column as float4. Per step: owner wave dumps raw column k to LDS (double-buffered), one
// barrier, all waves rank-1 update their active columns in registers. Output: LT (L
// transposed, LT[k][i] = L[i][k]) written IN PLACE over K (row k only ever touched by its
// owner wave: load-then-store program order). rd[k] = 1/sqrt(diag).
__global__ __launch_bounds__(1024) void k_chol2(float* __restrict__ Aw, float* __restrict__ rd) {
  int g = blockIdx.x;
  int w_s = __builtin_amdgcn_readfirstlane((int)(threadIdx.x >> 6));  // wave id, scalar
  int lane = threadIdx.x & 63;
  int r0 = 4 * lane;
  float* Ag = Aw + (size_t)g * NN * NN;
  float* rdg = rd + g * NN;
  __shared__ float cb[2][NN];
  float4 v[16];
#pragma unroll
  for (int cI = 0; cI < 16; cI++) {
    int j = cI * 16 + w_s;
    v[cI] = ((const float4*)(Ag + (size_t)j * NN))[lane];  // K symmetric: column j == row j
  }
  for (int k = 0; k < NN; k++) {
    float* cbb = cb[k & 1];
    bool own = (w_s == (k & 15));
    if (own) {
#pragma unroll
      for (int cI = 0; cI < 16; cI++)
        if (cI == (k >> 4)) ((float4*)cbb)[lane] = v[cI];  // raw column k
    }
    __syncthreads();
    float d = cbb[k];
    float invd = 1.0f / d;
    if (own) {
      float rs = rsqrtf(d);
#pragma unroll
      for (int cI = 0; cI < 16; cI++)
        if (cI == (k >> 4)) {
          if (r0 + 0 >= k) Ag[(size_t)k * NN + r0 + 0] = v[cI].x * rs;
          if (r0 + 1 >= k) Ag[(size_t)k * NN + r0 + 1] = v[cI].y * rs;
          if (r0 + 2 >= k) Ag[(size_t)k * NN + r0 + 2] = v[cI].z * rs;
          if (r0 + 3 >= k) Ag[(size_t)k * NN + r0 + 3] = v[cI].w * rs;
        }
      if (lane == 0) rdg[k] = rs;
    }
    float4 cc = make_float4(0.f, 0.f, 0.f, 0.f);
    if (r0 + 3 > k) cc = ((const float4*)cbb)[lane];  // hoisted shared-column read
#pragma unroll
    for (int cI = 0; cI < 16; cI++) {
      int j = cI * 16 + w_s;
      if (j > k) {  // wave-uniform (w_s scalar) -> scalar branch
        float s = cbb[j] * invd;
        if (r0 + 3 >= j) {
          v[cI].x = fmaf(-s, cc.x, v[cI].x);
          v[cI].y = fmaf(-s, cc.y, v[cI].y);
          v[cI].z = fmaf(-s, cc.z, v[cI].z);
          v[cI].w = fmaf(-s, cc.w, v[cI].w);
        }
      }
    }
  }
}

// ---------------- K2: Linv, one wave per column (forward substitution, LT layout) --------
__global__ __launch_bounds__(256) void k_linv(const float* __restrict__ LT,
                                              const float* __restrict__ rd,
                                              float* __restrict__ Linv) {
  int gw = (blockIdx.x * 256 + threadIdx.x) >> 6;  // global wave id, 2048 total
  int lane = threadIdx.x & 63;
  int g = gw >> 8;
  int j = gw & 255;
  const float* LTg = LT + (size_t)g * NN * NN;
  float* Og = Linv + (size_t)g * NN * NN;
  const float* rdg = rd + g * NN;
  float b0 = (lane == j) ? 1.f : 0.f;
  float b1 = (lane + 64 == j) ? 1.f : 0.f;
  float b2 = (lane + 128 == j) ? 1.f : 0.f;
  float b3 = (lane + 192 == j) ? 1.f : 0.f;
#pragma unroll
  for (int q = 0; q < 4; q++) {
    int i = lane + 64 * q;
    if (i < j) Og[(size_t)i * NN + j] = 0.f;
  }
  for (int k = j; k < NN; k++) {
    int src = k & 63;
    int reg = k >> 6;
    float bk;
    if (reg == 0) bk = __shfl(b0, src);
    else if (reg == 1) bk = __shfl(b1, src);
    else if (reg == 2) bk = __shfl(b2, src);
    else bk = __shfl(b3, src);
    float xk = bk * rdg[k];
    if (lane == 0) Og[(size_t)k * NN + j] = xk;
    const float* LTrow = LTg + (size_t)k * NN;
    int i0 = lane, i1 = lane + 64, i2 = lane + 128, i3 = lane + 192;
    if (i0 > k) b0 -= LTrow[i0] * xk;
    if (i1 > k) b1 -= LTrow[i1] * xk;
    if (i2 > k) b2 -= LTrow[i2] * xk;
    if (i3 > k) b3 -= LTrow[i3] * xk;
  }
}

// ---------------- K3: Kinv = Linv^T Linv (tiled SYRK-as-GEMM) ----------------
__global__ __launch_bounds__(256) void k_syrk(const float* __restrict__ Linv,
                                              float* __restrict__ Kinv) {
  int g = blockIdx.x >> 4;
  int tile = blockIdx.x & 15;
  int i0 = (tile >> 2) * 64, j0 = (tile & 3) * 64;
  const float* A = Linv + (size_t)g * NN * NN;
  float* O = Kinv + (size_t)g * NN * NN;
  __shared__ float sa[32][64], sb[32][64];
  int tx = threadIdx.x & 15, ty = threadIdx.x >> 4;
  float acc[4][4] = {{0.f}};
  for (int k0 = 0; k0 < NN; k0 += 32) {
    for (int e = threadIdx.x; e < 2048; e += 256) {
      int kk = e >> 6, cc = e & 63;
      sa[kk][cc] = A[(size_t)(k0 + kk) * NN + i0 + cc];
      sb[kk][cc] = A[(size_t)(k0 + kk) * NN + j0 + cc];
    }
    __syncthreads();
#pragma unroll 8
    for (int kk = 0; kk < 32; kk++) {
      float av[4], bv[4];
#pragma unroll
      for (int q = 0; q < 4; q++) { av[q] = sa[kk][ty * 4 + q]; bv[q] = sb[kk][tx * 4 + q]; }
#pragma unroll
      for (int q = 0; q < 4; q++)
#pragma unroll
        for (int r = 0; r < 4; r++) acc[q][r] += av[q] * bv[r];
    }
    __syncthreads();
  }
#pragma unroll
  for (int q = 0; q < 4; q++)
#pragma unroll
    for (int r = 0; r < 4; r++)
      O[(size_t)(i0 + ty * 4 + q) * NN + j0 + tx * 4 + r] = acc[q][r];
}

// ---------------- K3b: beta = Kinv @ y ----------------
__global__ __launch_bounds__(256) void k_beta(const float* __restrict__ Kinv,
                                              const float* __restrict__ y,
                                              float* __restrict__ betaw) {
  int g = blockIdx.x, n = threadIdx.x;
  __shared__ float ys[NN];
  ys[n] = y[n * S_DIM + g];
  __syncthreads();
  const float* Kg = Kinv + (size_t)g * NN * NN + (size_t)n * NN;
  float acc = 0.f;
  for (int m = 0; m < NN; m++) acc += Kg[m] * ys[m];
  betaw[g * NN + n] = acc;
}

// ---------------- K6: the big fused Q reduction ----------------
__global__ __launch_bounds__(256) void k_qsum(const float* __restrict__ u,
                                              const float* __restrict__ lkw,
                                              const float* __restrict__ Mw,
                                              const float* __restrict__ cvec,
                                              const float* __restrict__ betaw,
                                              const float* __restrict__ Kinv,
                                              float* __restrict__ covp, float* __restrict__ trp) {
  int p = blockIdx.x >> 2;
  int quarter = blockIdx.x & 3;
  int a = p >> 3, b = p & 7;
  int t = threadIdx.x;
  __shared__ float ub[NN * SA_DIM];
  __shared__ float Ms[100];
  __shared__ float sbv[NN];
  __shared__ float eb[NN];
  __shared__ float red[256];
  for (int idx = t; idx < NN * SA_DIM; idx += 256) ub[idx] = u[(size_t)b * NN * SA_DIM + idx];
  if (t < 100) Ms[t] = Mw[p * 100 + t];
  __syncthreads();
  {
    int m = t;
    float q = 0.f;
#pragma unroll
    for (int d = 0; d < SA_DIM; d++) {
      float v = 0.f;
#pragma unroll
      for (int e = 0; e < SA_DIM; e++) v += Ms[d * SA_DIM + e] * ub[m * SA_DIM + e];
      q += v * ub[m * SA_DIM + d];
    }
    sbv[m] = lkw[b * NN + m] + 0.5f * q;
    eb[m] = betaw[b * NN + m];
  }
  __syncthreads();
  int n = quarter * 64 + (t >> 2);
  int c = t & 3;
  float ua[SA_DIM];
#pragma unroll
  for (int d = 0; d < SA_DIM; d++) ua[d] = u[((size_t)a * NN + n) * SA_DIM + d];
  float va[SA_DIM];
#pragma unroll
  for (int d = 0; d < SA_DIM; d++) {
    float v = 0.f;
#pragma unroll
    for (int e = 0; e < SA_DIM; e++) v += Ms[d * SA_DIM + e] * ua[e];
    va[d] = v;
  }
  float qa = 0.f;
#pragma unroll
  for (int d = 0; d < SA_DIM; d++) qa += va[d] * ua[d];
  float pa = lkw[a * NN + n] + 0.5f * qa + cvec[p];
  float wa = betaw[a * NN + n];
  const float* Krow = Kinv + (size_t)a * NN * NN + (size_t)n * NN;
  float covacc = 0.f, tracc = 0.f;
  bool dg = (a == b);
  for (int ii = 0; ii < 64; ii++) {
    int mm = c + 4 * ii;
    float s = pa + sbv[mm];
#pragma unroll
    for (int d = 0; d < SA_DIM; d++) s += va[d] * ub[mm * SA_DIM + d];
    float e = __expf(s);
    covacc += eb[mm] * e;
    if (dg) tracc += Krow[mm] * e;
  }
  covacc *= wa;
  red[t] = covacc;
  __syncthreads();
  for (int st = 128; st > 0; st >>= 1) {
    if (t < st) red[t] += red[t + st];
    __syncthreads();
  }
  if (t == 0) covp[blockIdx.x] = red[0];
  if (dg) {
    red[t] = tracc;
    __syncthreads();
    for (int st = 128; st > 0; st >>= 1) {
      if (t < st) red[t] += red[t + st];
      __syncthreads();
    }
    if (t == 0) trp[a * 4 + quarter] = red[0];
  }
}

// ---------------- K7: mean + cross-cov reductions ----------------
__global__ __launch_bounds__(256) void k_meancross(const float* __restrict__ x,
                                                   const float* __restrict__ mf,
                                                   const float* __restrict__ cov,
                                                   const float* __restrict__ scales,
                                                   const float* __restrict__ Ainvw,
                                                   const float* __restrict__ aimw,
                                                   const float* __restrict__ mdcw,
                                                   const float* __restrict__ betaw,
                                                   float* __restrict__ meanw,
                                                   float* __restrict__ crossw) {
  int g = blockIdx.x;
  int i = threadIdx.x;
  __shared__ float Ai[100], cv[100], aims[SA_DIM], sc[SA_DIM], mfs[SA_DIM];
  __shared__ float red[256];
  if (i < 100) { Ai[i] = Ainvw[g * 100 + i]; cv[i] = cov[i]; }
  if (i < SA_DIM) { aims[i] = aimw[g * SA_DIM + i]; sc[i] = scales[g * SA_DIM + i]; mfs[i] = mf[i]; }
  __syncthreads();
  float xi[SA_DIM], nu[SA_DIM];
#pragma unroll
  for (int d = 0; d < SA_DIM; d++) { xi[d] = x[i * SA_DIM + d]; nu[d] = xi[d] - mfs[d]; }
  float sv[SA_DIM], ad[SA_DIM];
#pragma unroll
  for (int d = 0; d < SA_DIM; d++) {
    float s1 = 0.f, s2 = 0.f;
#pragma unroll
    for (int e = 0; e < SA_DIM; e++) { s1 += Ai[d * SA_DIM + e] * nu[e]; s2 += Ai[d * SA_DIM + e] * xi[e]; }
    sv[d] = s1;
    ad[d] = s2;
  }
  float mq = 0.f;
#pragma unroll
  for (int d = 0; d < SA_DIM; d++) mq += nu[d] * sv[d];
  float bg = betaw[g * NN + i];
  float mexp = mdcw[g] * __expf(-0.5f * mq);
  float cm = bg * mexp;
  float contrib[SA_DIM];
#pragma unroll
  for (int d = 0; d < SA_DIM; d++) {
    float ccm = sc[d] * aims[d];
#pragma unroll
    for (int j = 0; j < SA_DIM; j++) ccm += cv[d * SA_DIM + j] * ad[j];
    contrib[d] = mexp * ccm * bg;
  }
  red[i] = cm;
  __syncthreads();
  for (int st = 128; st > 0; st >>= 1) {
    if (i < st) red[i] += red[i + st];
    __syncthreads();
  }
  if (i == 0) meanw[g] = red[0];
  for (int d = 0; d < SA_DIM; d++) {
    __syncthreads();
    red[i] = contrib[d];
    __syncthreads();
    for (int st = 128; st > 0; st >>= 1) {
      if (i < st) red[i] += red[i + st];
      __syncthreads();
    }
    if (i == 0) crossw[d * S_DIM + g] = red[0];
  }
}

// ---------------- K8: final assembly ----------------
__global__ __launch_bounds__(64) void k_final(const float* __restrict__ covp,
                                              const float* __restrict__ trp,
                                              const float* __restrict__ meanw,
                                              const float* __restrict__ crossw,
                                              const float* __restrict__ cov,
                                              const float* __restrict__ eqc,
                                              const float* __restrict__ mf,
                                              float* __restrict__ out) {
  int p = threadIdx.x;
  if (p >= 64) return;
  int a = p >> 3, b = p & 7;
  float covq = covp[p * 4] + covp[p * 4 + 1] + covp[p * 4 + 2] + covp[p * 4 + 3];
  float ma = meanw[a], mb = meanw[b];
  float val = covq - ma * mb + cov[a * SA_DIM + b];
  if (a == b) {
    float tr = trp[a * 4] + trp[a * 4 + 1] + trp[a * 4 + 2] + trp[a * 4 + 3];
    val += eqc[a] - tr;
  }
  val += (crossw[a * S_DIM + b] - mf[a] * mb) + (crossw[b * S_DIM + a] - mf[b] * ma);
  out[S_DIM + p] = val;
  if (p < S_DIM) out[p] = meanw[p] + mf[p];
}

extern "C" void kernel_launch(void* const* d_in, const int* in_sizes, int n_in,
                              void* d_out, int out_size, void* d_ws, size_t ws_size,
                              hipStream_t stream) {
  const float* mf     = (const float*)d_in[0];  // [10]
  const float* cov    = (const float*)d_in[1];  // [10,10]
  const float* x      = (const float*)d_in[2];  // [256,10]
  const float* y      = (const float*)d_in[3];  // [256,8]
  const float* eqc    = (const float*)d_in[4];  // [8]
  const float* scales = (const float*)d_in[5];  // [8,10]
  const float* noise  = (const float*)d_in[6];  // [8]
  float* ws = (float*)d_ws;

  float* Kw    = ws + OFF_K;     // K, then LT in place
  float* Linv  = ws + OFF_LINV;
  float* Kinv  = ws + OFF_KINV;
  float* rd    = ws + OFF_RD;
  float* u     = ws + OFF_U;
  float* lkw   = ws + OFF_LK;
  float* Mw    = ws + OFF_M;
  float* cvec  = ws + OFF_C;
  float* Ainvw = ws + OFF_AINV;
  float* aimw  = ws + OFF_AIM;
  float* mdcw  = ws + OFF_MDC;
  float* betaw = ws + OFF_BETA;
  float* meanw = ws + OFF_MEAN;
  float* crossw= ws + OFF_CROSS;
  float* covp  = ws + OFF_COVP;
  float* trp   = ws + OFF_TRP;

  k_build_K<<<2048, 256, 0, stream>>>(x, eqc, scales, noise, Kw);
  k_prep<<<8, 256, 0, stream>>>(x, mf, eqc, scales, u, lkw);
  k_small<<<1, 64, 0, stream>>>(cov, scales, eqc, mf, Mw, cvec, Ainvw, aimw, mdcw);
  k_chol2<<<8, 1024, 0, stream>>>(Kw, rd);
  k_linv<<<512, 256, 0, stream>>>(Kw, rd, Linv);
  k_syrk<<<128, 256, 0, stream>>>(Linv, Kinv);
  k_beta<<<8, 256, 0, stream>>>(Kinv, y, betaw);
  k_qsum<<<256, 256, 0, stream>>>(u, lkw, Mw, cvec, betaw, Kinv, covp, trp);
  k_meancross<<<8, 256, 0, stream>>>(x, mf, cov, scales, Ainvw, aimw, mdcw, betaw, meanw, crossw);
  k_final<<<1, 64, 0, stream>>>(covp, trp, meanw, crossw, cov, eqc, mf, (float*)d_out);
}

// Round 3
// 611.179 us; speedup vs baseline: 6.3109x; 1.0063x over previous
//
#include <hip/hip_runtime.h>
#include <math.h>

#define S_DIM 8
#define SA_DIM 10
#define NN 256

// ---------------- workspace layout (float offsets) ----------------
constexpr size_t OFF_K     = 0;                          // 8*256*256  (K, then LT in-place: LT[k][i] = L[i][k])
constexpr size_t OFF_LINV  = OFF_K    + 8ull*NN*NN;      // 8*256*256
constexpr size_t OFF_KINV  = OFF_LINV + 8ull*NN*NN;      // 8*256*256
constexpr size_t OFF_RD    = OFF_KINV + 8ull*NN*NN;      // 8*256 reciprocal diag of L
constexpr size_t OFF_U     = OFF_RD   + 8*NN;            // 8*256*10  u = (x-mean)*inv_scales
constexpr size_t OFF_LK    = OFF_U    + 8*NN*SA_DIM;     // 8*256     log k(mean, x_n)
constexpr size_t OFF_M     = OFF_LK   + 8*NN;            // 64*100    M_ab
constexpr size_t OFF_C     = OFF_M    + 64*100;          // 64        -0.5*logdet R
constexpr size_t OFF_AINV  = OFF_C    + 64;              // 8*100
constexpr size_t OFF_AIM   = OFF_AINV + 800;             // 8*10      Ainv @ mean
constexpr size_t OFF_MDC   = OFF_AIM  + 80;              // 8         mean det coeff
constexpr size_t OFF_MEAN  = OFF_MDC  + 8;               // 8
constexpr size_t OFF_CROSS = OFF_MEAN + 8;               // 80  cross_cov[d][g]
constexpr size_t OFF_COVP  = OFF_CROSS+ 80;              // 256 partials
constexpr size_t OFF_TRP   = OFF_COVP + 256;             // 32  trace partials

// ---------------- Gauss-Jordan inverse, 10x10, no pivoting (matrices are I+PSD-like) ----
__device__ void gj_invert10(float A[SA_DIM][SA_DIM], float B[SA_DIM][SA_DIM], float* logdet) {
#pragma unroll
  for (int i = 0; i < SA_DIM; i++)
#pragma unroll
    for (int j = 0; j < SA_DIM; j++) B[i][j] = (i == j) ? 1.f : 0.f;
  float ld = 0.f;
#pragma unroll
  for (int k = 0; k < SA_DIM; k++) {
    float pv = A[k][k];
    ld += logf(pv);
    float ip = 1.f / pv;
#pragma unroll
    for (int j = 0; j < SA_DIM; j++) { A[k][j] *= ip; B[k][j] *= ip; }
#pragma unroll
    for (int r = 0; r < SA_DIM; r++) {
      if (r == k) continue;
      float f = A[r][k];
#pragma unroll
      for (int j = 0; j < SA_DIM; j++) { A[r][j] -= f * A[k][j]; B[r][j] -= f * B[k][j]; }
    }
  }
  *logdet = ld;
}

// ---------------- K-front: build K  |  prep u/lk  |  small 10x10 linear algebra --------
__global__ __launch_bounds__(256) void k_front(const float* __restrict__ x,
                                               const float* __restrict__ mf,
                                               const float* __restrict__ cov,
                                               const float* __restrict__ eqc,
                                               const float* __restrict__ scales,
                                               const float* __restrict__ noise,
                                               float* __restrict__ Kw,
                                               float* __restrict__ u,
                                               float* __restrict__ lkw,
                                               float* __restrict__ Mw, float* __restrict__ cvec,
                                               float* __restrict__ Ainvw, float* __restrict__ aimw,
                                               float* __restrict__ mdcw) {
  int blk = blockIdx.x;
  if (blk < 2048) {
    int g = blk >> 8;
    int n = blk & 255;
    int m = threadIdx.x;
    __shared__ float xs[NN * SA_DIM];
    __shared__ float isc[SA_DIM];
    for (int i = threadIdx.x; i < NN * SA_DIM; i += 256) xs[i] = x[i];
    if (threadIdx.x < SA_DIM) isc[threadIdx.x] = 1.0f / scales[g * SA_DIM + threadIdx.x];
    __syncthreads();
    float quad = 0.f;
#pragma unroll
    for (int d = 0; d < SA_DIM; d++) {
      float df = xs[n * SA_DIM + d] - xs[m * SA_DIM + d];
      quad += df * df * isc[d];
    }
    float v = eqc[g] * __expf(-0.5f * quad);
    if (m == n) v += noise[g];
    Kw[(size_t)g * NN * NN + (size_t)n * NN + m] = v;
  } else if (blk < 2056) {
    int g = blk - 2048;
    int n = threadIdx.x;
    float quad = 0.f;
#pragma unroll
    for (int d = 0; d < SA_DIM; d++) {
      float isc = 1.0f / scales[g * SA_DIM + d];
      float nu = x[n * SA_DIM + d] - mf[d];
      u[((size_t)g * NN + n) * SA_DIM + d] = nu * isc;
      quad += nu * nu * isc;
    }
    lkw[g * NN + n] = logf(eqc[g]) - 0.5f * quad;
  } else {
    int p = threadIdx.x;
    if (p >= 64) return;
    int a = p >> 3, b = p & 7;
    float A[SA_DIM][SA_DIM], B[SA_DIM][SA_DIM];
    for (int i = 0; i < SA_DIM; i++)
      for (int j = 0; j < SA_DIM; j++)
        A[i][j] = cov[i * SA_DIM + j] * (1.f / scales[a * SA_DIM + j] + 1.f / scales[b * SA_DIM + j]) +
                  ((i == j) ? 1.f : 0.f);
    float ld;
    gj_invert10(A, B, &ld);
    cvec[p] = -0.5f * ld;
    for (int i = 0; i < SA_DIM; i++)
      for (int j = 0; j < SA_DIM; j++) {
        float v = 0.f;
        for (int k = 0; k < SA_DIM; k++) v += B[i][k] * cov[k * SA_DIM + j];
        Mw[p * 100 + i * SA_DIM + j] = v;
      }
    if (b == 0) {
      int g = a;
      for (int i = 0; i < SA_DIM; i++)
        for (int j = 0; j < SA_DIM; j++)
          A[i][j] = cov[i * SA_DIM + j] + ((i == j) ? scales[g * SA_DIM + j] : 0.f);
      float ld2;
      gj_invert10(A, B, &ld2);
      for (int i = 0; i < SA_DIM; i++)
        for (int j = 0; j < SA_DIM; j++) Ainvw[g * 100 + i * SA_DIM + j] = B[i][j];
      for (int i = 0; i < SA_DIM; i++) {
        float v = 0.f;
        for (int j = 0; j < SA_DIM; j++) v += B[i][j] * mf[j];
        aimw[g * SA_DIM + i] = v;
      }
      for (int i = 0; i < SA_DIM; i++)
        for (int j = 0; j < SA_DIM; j++)
          A[i][j] = cov[i * SA_DIM + j] * (1.f / scales[g * SA_DIM + j]) + ((i == j) ? 1.f : 0.f);
      float ld3;
      gj_invert10(A, B, &ld3);
      mdcw[g] = eqc[g] * __expf(-0.5f * ld3);
    }
  }
}

// ---------------- K1: panel-blocked Cholesky, one block (1024 thr) per g ----------------
// Wave w owns contiguous cols [16w,16w+16); lane holds rows [4l,4l+4) per col (float4).
// Per panel p (cols 16p..16p+15, owned by wave p): waves w>=p apply the 16 rank-1 updates
// of panel p-1 (from LDS, batched, no inner barriers); wave p then factors its 16 cols
// entirely in-register via __shfl (pivot + scalars are lane/component extractions) and
// broadcasts the finalized panel to LDS. ONE barrier per panel (16 total). LT (L
// transposed) + rd written to global only after the loop (no per-step vmcnt drains).
__global__ __launch_bounds__(1024) void k_chol3(float* __restrict__ Aw, float* __restrict__ rd) {
  int g = blockIdx.x;
  int w_s = __builtin_amdgcn_readfirstlane((int)(threadIdx.x >> 6));
  int lane = threadIdx.x & 63;
  float* Ag = Aw + (size_t)g * NN * NN;
  float* rdg = rd + g * NN;
  __shared__ __align__(16) float Pbuf[2][16][260];
  float4 v[16];
#pragma unroll
  for (int cI = 0; cI < 16; cI++)
    v[cI] = ((const float4*)(Ag + (size_t)(16 * w_s + cI) * NN))[lane];  // K symmetric: col==row
  for (int p = 0; p < 16; p++) {
    if (p > 0 && w_s >= p) {
      const float* P = &Pbuf[(p - 1) & 1][0][0];
#pragma unroll
      for (int k = 0; k < 16; k++) {
        const float* Pk = P + k * 260;
        float4 pk = *(const float4*)(Pk + 4 * lane);
        float4 s0 = *(const float4*)(Pk + 16 * w_s + 0);
        float4 s1 = *(const float4*)(Pk + 16 * w_s + 4);
        float4 s2 = *(const float4*)(Pk + 16 * w_s + 8);
        float4 s3 = *(const float4*)(Pk + 16 * w_s + 12);
#define UPD4(cc, sv)                           \
        v[cc].x = fmaf(-(sv), pk.x, v[cc].x);  \
        v[cc].y = fmaf(-(sv), pk.y, v[cc].y);  \
        v[cc].z = fmaf(-(sv), pk.z, v[cc].z);  \
        v[cc].w = fmaf(-(sv), pk.w, v[cc].w);
        UPD4(0, s0.x) UPD4(1, s0.y) UPD4(2, s0.z) UPD4(3, s0.w)
        UPD4(4, s1.x) UPD4(5, s1.y) UPD4(6, s1.z) UPD4(7, s1.w)
        UPD4(8, s2.x) UPD4(9, s2.y) UPD4(10, s2.z) UPD4(11, s2.w)
        UPD4(12, s3.x) UPD4(13, s3.y) UPD4(14, s3.z) UPD4(15, s3.w)
#undef UPD4
      }
    }
    if (w_s == p) {
#pragma unroll
      for (int cI = 0; cI < 16; cI++) {
        int jl = 4 * p + (cI >> 2);
        float mc = (cI & 3) == 0 ? v[cI].x : (cI & 3) == 1 ? v[cI].y
                 : (cI & 3) == 2 ? v[cI].z : v[cI].w;
        float d = __shfl(mc, jl);
        float rs = rsqrtf(d);
        v[cI].x *= rs; v[cI].y *= rs; v[cI].z *= rs; v[cI].w *= rs;
        if (lane == 0) rdg[16 * p + cI] = rs;
#pragma unroll
        for (int cI2 = cI + 1; cI2 < 16; cI2++) {
          float c2 = (cI2 & 3) == 0 ? v[cI].x : (cI2 & 3) == 1 ? v[cI].y
                   : (cI2 & 3) == 2 ? v[cI].z : v[cI].w;
          float s = __shfl(c2, 4 * p + (cI2 >> 2));
          v[cI2].x = fmaf(-s, v[cI].x, v[cI2].x);
          v[cI2].y = fmaf(-s, v[cI].y, v[cI2].y);
          v[cI2].z = fmaf(-s, v[cI].z, v[cI2].z);
          v[cI2].w = fmaf(-s, v[cI].w, v[cI2].w);
        }
      }
#pragma unroll
      for (int cI = 0; cI < 16; cI++)
        *(float4*)(&Pbuf[p & 1][cI][0] + 4 * lane) = v[cI];
    }
    __syncthreads();
  }
#pragma unroll
  for (int cI = 0; cI < 16; cI++)
    ((float4*)(Ag + (size_t)(16 * w_s + cI) * NN))[lane] = v[cI];  // LT row = L column
}

// ---------------- K2: Linv, one wave per column (forward substitution, LT layout) --------
__global__ __launch_bounds__(256) void k_linv(const float* __restrict__ LT,
                                              const float* __restrict__ rd,
                                              float* __restrict__ Linv) {
  int gw = (blockIdx.x * 256 + threadIdx.x) >> 6;  // global wave id, 2048 total
  int lane = threadIdx.x & 63;
  int g = gw >> 8;
  int j = gw & 255;
  const float* LTg = LT + (size_t)g * NN * NN;
  float* Og = Linv + (size_t)g * NN * NN;
  const float* rdg = rd + g * NN;
  float b0 = (lane == j) ? 1.f : 0.f;
  float b1 = (lane + 64 == j) ? 1.f : 0.f;
  float b2 = (lane + 128 == j) ? 1.f : 0.f;
  float b3 = (lane + 192 == j) ? 1.f : 0.f;
#pragma unroll
  for (int q = 0; q < 4; q++) {
    int i = lane + 64 * q;
    if (i < j) Og[(size_t)i * NN + j] = 0.f;
  }
  for (int k = j; k < NN; k++) {
    int src = k & 63;
    int reg = k >> 6;
    float bk;
    if (reg == 0) bk = __shfl(b0, src);
    else if (reg == 1) bk = __shfl(b1, src);
    else if (reg == 2) bk = __shfl(b2, src);
    else bk = __shfl(b3, src);
    float xk = bk * rdg[k];
    if (lane == 0) Og[(size_t)k * NN + j] = xk;
    const float* LTrow = LTg + (size_t)k * NN;
    int i0 = lane, i1 = lane + 64, i2 = lane + 128, i3 = lane + 192;
    if (i0 > k) b0 -= LTrow[i0] * xk;
    if (i1 > k) b1 -= LTrow[i1] * xk;
    if (i2 > k) b2 -= LTrow[i2] * xk;
    if (i3 > k) b3 -= LTrow[i3] * xk;
  }
}

// ---------------- K3: Kinv = Linv^T Linv (tiled SYRK-as-GEMM) ----------------
__global__ __launch_bounds__(256) void k_syrk(const float* __restrict__ Linv,
                                              float* __restrict__ Kinv) {
  int g = blockIdx.x >> 4;
  int tile = blockIdx.x & 15;
  int i0 = (tile >> 2) * 64, j0 = (tile & 3) * 64;
  const float* A = Linv + (size_t)g * NN * NN;
  float* O = Kinv + (size_t)g * NN * NN;
  __shared__ float sa[32][64], sb[32][64];
  int tx = threadIdx.x & 15, ty = threadIdx.x >> 4;
  float acc[4][4] = {{0.f}};
  for (int k0 = 0; k0 < NN; k0 += 32) {
    for (int e = threadIdx.x; e < 2048; e += 256) {
      int kk = e >> 6, cc = e & 63;
      sa[kk][cc] = A[(size_t)(k0 + kk) * NN + i0 + cc];
      sb[kk][cc] = A[(size_t)(k0 + kk) * NN + j0 + cc];
    }
    __syncthreads();
#pragma unroll 8
    for (int kk = 0; kk < 32; kk++) {
      float av[4], bv[4];
#pragma unroll
      for (int q = 0; q < 4; q++) { av[q] = sa[kk][ty * 4 + q]; bv[q] = sb[kk][tx * 4 + q]; }
#pragma unroll
      for (int q = 0; q < 4; q++)
#pragma unroll
        for (int r = 0; r < 4; r++) acc[q][r] += av[q] * bv[r];
    }
    __syncthreads();
  }
#pragma unroll
  for (int q = 0; q < 4; q++)
#pragma unroll
    for (int r = 0; r < 4; r++)
      O[(size_t)(i0 + ty * 4 + q) * NN + j0 + tx * 4 + r] = acc[q][r];
}

// ---------------- K-back: fused Q reduction (blocks 0..255) + mean/cross (256..263) ------
__global__ __launch_bounds__(256) void k_back(const float* __restrict__ u,
                                              const float* __restrict__ lkw,
                                              const float* __restrict__ Mw,
                                              const float* __restrict__ cvec,
                                              const float* __restrict__ Kinv,
                                              const float* __restrict__ y,
                                              const float* __restrict__ x,
                                              const float* __restrict__ mf,
                                              const float* __restrict__ cov,
                                              const float* __restrict__ scales,
                                              const float* __restrict__ Ainvw,
                                              const float* __restrict__ aimw,
                                              const float* __restrict__ mdcw,
                                              float* __restrict__ covp, float* __restrict__ trp,
                                              float* __restrict__ meanw, float* __restrict__ crossw) {
  int blk = blockIdx.x;
  int t = threadIdx.x;
  if (blk < 256) {
    int p = blk >> 2;
    int quarter = blk & 3;
    int a = p >> 3, b = p & 7;
    __shared__ __align__(16) float ub[NN * SA_DIM];
    __shared__ float Ms[100];
    __shared__ float sbv[NN];
    __shared__ __align__(16) float eb[NN];
    __shared__ __align__(16) float ysb[NN];
    __shared__ __align__(16) float ysa[NN];
    __shared__ float red[256];
    for (int idx = t; idx < NN * SA_DIM; idx += 256) ub[idx] = u[(size_t)b * NN * SA_DIM + idx];
    if (t < 100) Ms[t] = Mw[p * 100 + t];
    ysb[t] = y[t * S_DIM + b];
    ysa[t] = y[t * S_DIM + a];
    __syncthreads();
    {
      // beta_b[t] inline (Kinv symmetric: row t == col t)
      const float4* Kb = (const float4*)(Kinv + (size_t)b * NN * NN + (size_t)t * NN);
      float acc = 0.f;
      for (int m4 = 0; m4 < 64; m4++) {
        float4 kv = Kb[m4];
        float4 yv = ((const float4*)ysb)[m4];
        acc += kv.x * yv.x + kv.y * yv.y + kv.z * yv.z + kv.w * yv.w;
      }
      eb[t] = acc;
      int m = t;
      float q = 0.f;
#pragma unroll
      for (int d = 0; d < SA_DIM; d++) {
        float v = 0.f;
#pragma unroll
        for (int e = 0; e < SA_DIM; e++) v += Ms[d * SA_DIM + e] * ub[m * SA_DIM + e];
        q += v * ub[m * SA_DIM + d];
      }
      sbv[m] = lkw[b * NN + m] + 0.5f * q;
    }
    __syncthreads();
    int n = quarter * 64 + (t >> 2);
    int c = t & 3;
    float ua[SA_DIM];
#pragma unroll
    for (int d = 0; d < SA_DIM; d++) ua[d] = u[((size_t)a * NN + n) * SA_DIM + d];
    float va[SA_DIM];
#pragma unroll
    for (int d = 0; d < SA_DIM; d++) {
      float v = 0.f;
#pragma unroll
      for (int e = 0; e < SA_DIM; e++) v += Ms[d * SA_DIM + e] * ua[e];
      va[d] = v;
    }
    float qa = 0.f;
#pragma unroll
    for (int d = 0; d < SA_DIM; d++) qa += va[d] * ua[d];
    float pa = lkw[a * NN + n] + 0.5f * qa + cvec[p];
    float wa;
    if (a == b) {
      wa = eb[n];
    } else {
      const float4* Ka = (const float4*)(Kinv + (size_t)a * NN * NN + (size_t)n * NN);
      float acc = 0.f;
      for (int m4 = 0; m4 < 64; m4++) {
        float4 kv = Ka[m4];
        float4 yv = ((const float4*)ysa)[m4];
        acc += kv.x * yv.x + kv.y * yv.y + kv.z * yv.z + kv.w * yv.w;
      }
      wa = acc;
    }
    const float* Krow = Kinv + (size_t)a * NN * NN + (size_t)n * NN;
    float covacc = 0.f, tracc = 0.f;
    bool dg = (a == b);
    for (int ii = 0; ii < 64; ii++) {
      int mm = c + 4 * ii;
      float s = pa + sbv[mm];
#pragma unroll
      for (int d = 0; d < SA_DIM; d++) s += va[d] * ub[mm * SA_DIM + d];
      float e = __expf(s);
      covacc += eb[mm] * e;
      if (dg) tracc += Krow[mm] * e;
    }
    covacc *= wa;
    red[t] = covacc;
    __syncthreads();
    for (int st = 128; st > 0; st >>= 1) {
      if (t < st) red[t] += red[t + st];
      __syncthreads();
    }
    if (t == 0) covp[blk] = red[0];
    if (dg) {
      red[t] = tracc;
      __syncthreads();
      for (int st = 128; st > 0; st >>= 1) {
        if (t < st) red[t] += red[t + st];
        __syncthreads();
      }
      if (t == 0) trp[a * 4 + quarter] = red[0];
    }
  } else {
    int g = blk - 256;
    int i = t;
    __shared__ float Ai[100], cv[100], aims[SA_DIM], sc[SA_DIM], mfs[SA_DIM];
    __shared__ __align__(16) float ys[NN];
    __shared__ float red[256];
    if (i < 100) { Ai[i] = Ainvw[g * 100 + i]; cv[i] = cov[i]; }
    if (i < SA_DIM) { aims[i] = aimw[g * SA_DIM + i]; sc[i] = scales[g * SA_DIM + i]; mfs[i] = mf[i]; }
    ys[i] = y[i * S_DIM + g];
    __syncthreads();
    // beta_g[i] inline
    float bg;
    {
      const float4* Kg = (const float4*)(Kinv + (size_t)g * NN * NN + (size_t)i * NN);
      float acc = 0.f;
      for (int m4 = 0; m4 < 64; m4++) {
        float4 kv = Kg[m4];
        float4 yv = ((const float4*)ys)[m4];
        acc += kv.x * yv.x + kv.y * yv.y + kv.z * yv.z + kv.w * yv.w;
      }
      bg = acc;
    }
    float xi[SA_DIM], nu[SA_DIM];
#pragma unroll
    for (int d = 0; d < SA_DIM; d++) { xi[d] = x[i * SA_DIM + d]; nu[d] = xi[d] - mfs[d]; }
    float sv[SA_DIM], ad[SA_DIM];
#pragma unroll
    for (int d = 0; d < SA_DIM; d++) {
      float s1 = 0.f, s2 = 0.f;
#pragma unroll
      for (int e = 0; e < SA_DIM; e++) { s1 += Ai[d * SA_DIM + e] * nu[e]; s2 += Ai[d * SA_DIM + e] * xi[e]; }
      sv[d] = s1;
      ad[d] = s2;
    }
    float mq = 0.f;
#pragma unroll
    for (int d = 0; d < SA_DIM; d++) mq += nu[d] * sv[d];
    float mexp = mdcw[g] * __expf(-0.5f * mq);
    float cm = bg * mexp;
    float contrib[SA_DIM];
#pragma unroll
    for (int d = 0; d < SA_DIM; d++) {
      float ccm = sc[d] * aims[d];
#pragma unroll
      for (int j = 0; j < SA_DIM; j++) ccm += cv[d * SA_DIM + j] * ad[j];
      contrib[d] = mexp * ccm * bg;
    }
    red[i] = cm;
    __syncthreads();
    for (int st = 128; st > 0; st >>= 1) {
      if (i < st) red[i] += red[i + st];
      __syncthreads();
    }
    if (i == 0) meanw[g] = red[0];
    for (int d = 0; d < SA_DIM; d++) {
      __syncthreads();
      red[i] = contrib[d];
      __syncthreads();
      for (int st = 128; st > 0; st >>= 1) {
        if (i < st) red[i] += red[i + st];
        __syncthreads();
      }
      if (i == 0) crossw[d * S_DIM + g] = red[0];
    }
  }
}

// ---------------- K8: final assembly ----------------
__global__ __launch_bounds__(64) void k_final(const float* __restrict__ covp,
                                              const float* __restrict__ trp,
                                              const float* __restrict__ meanw,
                                              const float* __restrict__ crossw,
                                              const float* __restrict__ cov,
                                              const float* __restrict__ eqc,
                                              const float* __restrict__ mf,
                                              float* __restrict__ out) {
  int p = threadIdx.x;
  if (p >= 64) return;
  int a = p >> 3, b = p & 7;
  float covq = covp[p * 4] + covp[p * 4 + 1] + covp[p * 4 + 2] + covp[p * 4 + 3];
  float ma = meanw[a], mb = meanw[b];
  float val = covq - ma * mb + cov[a * SA_DIM + b];
  if (a == b) {
    float tr = trp[a * 4] + trp[a * 4 + 1] + trp[a * 4 + 2] + trp[a * 4 + 3];
    val += eqc[a] - tr;
  }
  val += (crossw[a * S_DIM + b] - mf[a] * mb) + (crossw[b * S_DIM + a] - mf[b] * ma);
  out[S_DIM + p] = val;
  if (p < S_DIM) out[p] = meanw[p] + mf[p];
}

extern "C" void kernel_launch(void* const* d_in, const int* in_sizes, int n_in,
                              void* d_out, int out_size, void* d_ws, size_t ws_size,
                              hipStream_t stream) {
  const float* mf     = (const float*)d_in[0];  // [10]
  const float* cov    = (const float*)d_in[1];  // [10,10]
  const float* x      = (const float*)d_in[2];  // [256,10]
  const float* y      = (const float*)d_in[3];  // [256,8]
  const float* eqc    = (const float*)d_in[4];  // [8]
  const float* scales = (const float*)d_in[5];  // [8,10]
  const float* noise  = (const float*)d_in[6];  // [8]
  float* ws = (float*)d_ws;

  float* Kw    = ws + OFF_K;     // K, then LT in place
  float* Linv  = ws + OFF_LINV;
  float* Kinv  = ws + OFF_KINV;
  float* rd    = ws + OFF_RD;
  float* u     = ws + OFF_U;
  float* lkw   = ws + OFF_LK;
  float* Mw    = ws + OFF_M;
  float* cvec  = ws + OFF_C;
  float* Ainvw = ws + OFF_AINV;
  float* aimw  = ws + OFF_AIM;
  float* mdcw  = ws + OFF_MDC;
  float* meanw = ws + OFF_MEAN;
  float* crossw= ws + OFF_CROSS;
  float* covp  = ws + OFF_COVP;
  float* trp   = ws + OFF_TRP;

  k_front<<<2057, 256, 0, stream>>>(x, mf, cov, eqc, scales, noise, Kw, u, lkw, Mw, cvec,
                                    Ainvw, aimw, mdcw);
  k_chol3<<<8, 1024, 0, stream>>>(Kw, rd);
  k_linv<<<512, 256, 0, stream>>>(Kw, rd, Linv);
  k_syrk<<<128, 256, 0, stream>>>(Linv, Kinv);
  k_back<<<264, 256, 0, stream>>>(u, lkw, Mw, cvec, Kinv, y, x, mf, cov, scales,
                                  Ainvw, aimw, mdcw, covp, trp, meanw, crossw);
  k_final<<<1, 64, 0, stream>>>(covp, trp, meanw, crossw, cov, eqc, mf, (float*)d_out);
}

// Round 4
// 441.091 us; speedup vs baseline: 8.7445x; 1.3856x over previous
//
#include <hip/hip_runtime.h>
#include <math.h>

#define S_DIM 8
#define SA_DIM 10
#define NN 256

// ---------------- workspace layout (float offsets) ----------------
constexpr size_t OFF_K     = 0;                          // 8*256*256  (K, then LT in-place: LT[k][i] = L[i][k])
constexpr size_t OFF_LINV  = OFF_K    + 8ull*NN*NN;      // 8*256*256
constexpr size_t OFF_KINV  = OFF_LINV + 8ull*NN*NN;      // 8*256*256
constexpr size_t OFF_RD    = OFF_KINV + 8ull*NN*NN;      // 8*256 reciprocal diag of L
constexpr size_t OFF_U     = OFF_RD   + 8*NN;            // 8*256*10  u = (x-mean)*inv_scales
constexpr size_t OFF_LK    = OFF_U    + 8*NN*SA_DIM;     // 8*256     log k(mean, x_n)
constexpr size_t OFF_M     = OFF_LK   + 8*NN;            // 64*100    M_ab
constexpr size_t OFF_C     = OFF_M    + 64*100;          // 64        -0.5*logdet R
constexpr size_t OFF_AINV  = OFF_C    + 64;              // 8*100
constexpr size_t OFF_AIM   = OFF_AINV + 800;             // 8*10      Ainv @ mean
constexpr size_t OFF_MDC   = OFF_AIM  + 80;              // 8         mean det coeff
constexpr size_t OFF_MEAN  = OFF_MDC  + 8;               // 8
constexpr size_t OFF_CROSS = OFF_MEAN + 8;               // 80  cross_cov[d][g]
constexpr size_t OFF_COVP  = OFF_CROSS+ 80;              // 256 partials
constexpr size_t OFF_TRP   = OFF_COVP + 256;             // 32  trace partials

// scalarize a wave-uniform float (broadcast LDS read result) into an SGPR
__device__ __forceinline__ float rf(float x) {
  return __int_as_float(__builtin_amdgcn_readfirstlane(__float_as_int(x)));
}

// ---------------- Gauss-Jordan inverse, 10x10, no pivoting (matrices are I+PSD-like) ----
__device__ void gj_invert10(float A[SA_DIM][SA_DIM], float B[SA_DIM][SA_DIM], float* logdet) {
#pragma unroll
  for (int i = 0; i < SA_DIM; i++)
#pragma unroll
    for (int j = 0; j < SA_DIM; j++) B[i][j] = (i == j) ? 1.f : 0.f;
  float ld = 0.f;
#pragma unroll
  for (int k = 0; k < SA_DIM; k++) {
    float pv = A[k][k];
    ld += logf(pv);
    float ip = 1.f / pv;
#pragma unroll
    for (int j = 0; j < SA_DIM; j++) { A[k][j] *= ip; B[k][j] *= ip; }
#pragma unroll
    for (int r = 0; r < SA_DIM; r++) {
      if (r == k) continue;
      float f = A[r][k];
#pragma unroll
      for (int j = 0; j < SA_DIM; j++) { A[r][j] -= f * A[k][j]; B[r][j] -= f * B[k][j]; }
    }
  }
  *logdet = ld;
}

// ---------------- K-front: build K  |  prep u/lk  |  small 10x10 linear algebra --------
__global__ __launch_bounds__(256) void k_front(const float* __restrict__ x,
                                               const float* __restrict__ mf,
                                               const float* __restrict__ cov,
                                               const float* __restrict__ eqc,
                                               const float* __restrict__ scales,
                                               const float* __restrict__ noise,
                                               float* __restrict__ Kw,
                                               float* __restrict__ u,
                                               float* __restrict__ lkw,
                                               float* __restrict__ Mw, float* __restrict__ cvec,
                                               float* __restrict__ Ainvw, float* __restrict__ aimw,
                                               float* __restrict__ mdcw) {
  int blk = blockIdx.x;
  if (blk < 2048) {
    int g = blk >> 8;
    int n = blk & 255;
    int m = threadIdx.x;
    __shared__ float xs[NN * SA_DIM];
    __shared__ float isc[SA_DIM];
    for (int i = threadIdx.x; i < NN * SA_DIM; i += 256) xs[i] = x[i];
    if (threadIdx.x < SA_DIM) isc[threadIdx.x] = 1.0f / scales[g * SA_DIM + threadIdx.x];
    __syncthreads();
    float quad = 0.f;
#pragma unroll
    for (int d = 0; d < SA_DIM; d++) {
      float df = xs[n * SA_DIM + d] - xs[m * SA_DIM + d];
      quad += df * df * isc[d];
    }
    float v = eqc[g] * __expf(-0.5f * quad);
    if (m == n) v += noise[g];
    Kw[(size_t)g * NN * NN + (size_t)n * NN + m] = v;
  } else if (blk < 2056) {
    int g = blk - 2048;
    int n = threadIdx.x;
    float quad = 0.f;
#pragma unroll
    for (int d = 0; d < SA_DIM; d++) {
      float isc = 1.0f / scales[g * SA_DIM + d];
      float nu = x[n * SA_DIM + d] - mf[d];
      u[((size_t)g * NN + n) * SA_DIM + d] = nu * isc;
      quad += nu * nu * isc;
    }
    lkw[g * NN + n] = logf(eqc[g]) - 0.5f * quad;
  } else {
    int p = threadIdx.x;
    if (p >= 64) return;
    int a = p >> 3, b = p & 7;
    float A[SA_DIM][SA_DIM], B[SA_DIM][SA_DIM];
    for (int i = 0; i < SA_DIM; i++)
      for (int j = 0; j < SA_DIM; j++)
        A[i][j] = cov[i * SA_DIM + j] * (1.f / scales[a * SA_DIM + j] + 1.f / scales[b * SA_DIM + j]) +
                  ((i == j) ? 1.f : 0.f);
    float ld;
    gj_invert10(A, B, &ld);
    cvec[p] = -0.5f * ld;
    for (int i = 0; i < SA_DIM; i++)
      for (int j = 0; j < SA_DIM; j++) {
        float v = 0.f;
        for (int k = 0; k < SA_DIM; k++) v += B[i][k] * cov[k * SA_DIM + j];
        Mw[p * 100 + i * SA_DIM + j] = v;
      }
    if (b == 0) {
      int g = a;
      for (int i = 0; i < SA_DIM; i++)
        for (int j = 0; j < SA_DIM; j++)
          A[i][j] = cov[i * SA_DIM + j] + ((i == j) ? scales[g * SA_DIM + j] : 0.f);
      float ld2;
      gj_invert10(A, B, &ld2);
      for (int i = 0; i < SA_DIM; i++)
        for (int j = 0; j < SA_DIM; j++) Ainvw[g * 100 + i * SA_DIM + j] = B[i][j];
      for (int i = 0; i < SA_DIM; i++) {
        float v = 0.f;
        for (int j = 0; j < SA_DIM; j++) v += B[i][j] * mf[j];
        aimw[g * SA_DIM + i] = v;
      }
      for (int i = 0; i < SA_DIM; i++)
        for (int j = 0; j < SA_DIM; j++)
          A[i][j] = cov[i * SA_DIM + j] * (1.f / scales[g * SA_DIM + j]) + ((i == j) ? 1.f : 0.f);
      float ld3;
      gj_invert10(A, B, &ld3);
      mdcw[g] = eqc[g] * __expf(-0.5f * ld3);
    }
  }
}

// ---------------- K1: panel-blocked Cholesky, one block (1024 thr) per g ----------------
// Wave w owns contiguous cols [16w,16w+16); lane holds rows [4l,4l+4) per col (float4).
// __launch_bounds__(1024,4): 4 waves/EU -> VGPR cap 128 (v[16]=64 data regs + working set
// fits; previous build capped at 64 and spilled the whole array to scratch -> 365us).
// Panel scalars (wave-uniform LDS broadcasts) go to SGPRs via readfirstlane.
__global__ __launch_bounds__(1024, 4) void k_chol3(float* __restrict__ Aw, float* __restrict__ rd) {
  int g = blockIdx.x;
  int w_s = __builtin_amdgcn_readfirstlane((int)(threadIdx.x >> 6));
  int lane = threadIdx.x & 63;
  float* Ag = Aw + (size_t)g * NN * NN;
  float* rdg = rd + g * NN;
  __shared__ __align__(16) float Pbuf[2][16][260];
  float4 v[16];
#pragma unroll
  for (int cI = 0; cI < 16; cI++)
    v[cI] = ((const float4*)(Ag + (size_t)(16 * w_s + cI) * NN))[lane];  // K symmetric: col==row
  for (int p = 0; p < 16; p++) {
    if (p > 0 && w_s >= p) {
      const float* P = &Pbuf[(p - 1) & 1][0][0];
#pragma unroll
      for (int k = 0; k < 16; k++) {
        const float* Pk = P + k * 260;
        float4 pk = *(const float4*)(Pk + 4 * lane);
        float4 sb0 = *(const float4*)(Pk + 16 * w_s + 0);
        float4 sb1 = *(const float4*)(Pk + 16 * w_s + 4);
        float4 sb2 = *(const float4*)(Pk + 16 * w_s + 8);
        float4 sb3 = *(const float4*)(Pk + 16 * w_s + 12);
        float s0 = rf(sb0.x), s1 = rf(sb0.y), s2 = rf(sb0.z), s3 = rf(sb0.w);
        float s4 = rf(sb1.x), s5 = rf(sb1.y), s6 = rf(sb1.z), s7 = rf(sb1.w);
        float s8 = rf(sb2.x), s9 = rf(sb2.y), s10 = rf(sb2.z), s11 = rf(sb2.w);
        float s12 = rf(sb3.x), s13 = rf(sb3.y), s14 = rf(sb3.z), s15 = rf(sb3.w);
#define UPD4(cc, sv)                           \
        v[cc].x = fmaf(-(sv), pk.x, v[cc].x);  \
        v[cc].y = fmaf(-(sv), pk.y, v[cc].y);  \
        v[cc].z = fmaf(-(sv), pk.z, v[cc].z);  \
        v[cc].w = fmaf(-(sv), pk.w, v[cc].w);
        UPD4(0, s0) UPD4(1, s1) UPD4(2, s2) UPD4(3, s3)
        UPD4(4, s4) UPD4(5, s5) UPD4(6, s6) UPD4(7, s7)
        UPD4(8, s8) UPD4(9, s9) UPD4(10, s10) UPD4(11, s11)
        UPD4(12, s12) UPD4(13, s13) UPD4(14, s14) UPD4(15, s15)
#undef UPD4
      }
    }
    if (w_s == p) {
#pragma unroll
      for (int cI = 0; cI < 16; cI++) {
        int jl = 4 * p + (cI >> 2);
        float mc = (cI & 3) == 0 ? v[cI].x : (cI & 3) == 1 ? v[cI].y
                 : (cI & 3) == 2 ? v[cI].z : v[cI].w;
        float d = __shfl(mc, jl);
        float rs = rsqrtf(d);
        v[cI].x *= rs; v[cI].y *= rs; v[cI].z *= rs; v[cI].w *= rs;
        if (lane == 0) rdg[16 * p + cI] = rs;
#pragma unroll
        for (int cI2 = cI + 1; cI2 < 16; cI2++) {
          float c2 = (cI2 & 3) == 0 ? v[cI].x : (cI2 & 3) == 1 ? v[cI].y
                   : (cI2 & 3) == 2 ? v[cI].z : v[cI].w;
          float s = __shfl(c2, 4 * p + (cI2 >> 2));
          v[cI2].x = fmaf(-s, v[cI].x, v[cI2].x);
          v[cI2].y = fmaf(-s, v[cI].y, v[cI2].y);
          v[cI2].z = fmaf(-s, v[cI].z, v[cI2].z);
          v[cI2].w = fmaf(-s, v[cI].w, v[cI2].w);
        }
      }
#pragma unroll
      for (int cI = 0; cI < 16; cI++)
        *(float4*)(&Pbuf[p & 1][cI][0] + 4 * lane) = v[cI];
    }
    __syncthreads();
  }
#pragma unroll
  for (int cI = 0; cI < 16; cI++)
    ((float4*)(Ag + (size_t)(16 * w_s + cI) * NN))[lane] = v[cI];  // LT row = L column
}

// ---------------- K2: Linv, one wave per column (forward substitution, LT layout) --------
__global__ __launch_bounds__(256) void k_linv(const float* __restrict__ LT,
                                              const float* __restrict__ rd,
                                              float* __restrict__ Linv) {
  int gw = (blockIdx.x * 256 + threadIdx.x) >> 6;  // global wave id, 2048 total
  int lane = threadIdx.x & 63;
  int g = gw >> 8;
  int j = gw & 255;
  const float* LTg = LT + (size_t)g * NN * NN;
  float* Og = Linv + (size_t)g * NN * NN;
  const float* rdg = rd + g * NN;
  float b0 = (lane == j) ? 1.f : 0.f;
  float b1 = (lane + 64 == j) ? 1.f : 0.f;
  float b2 = (lane + 128 == j) ? 1.f : 0.f;
  float b3 = (lane + 192 == j) ? 1.f : 0.f;
#pragma unroll
  for (int q = 0; q < 4; q++) {
    int i = lane + 64 * q;
    if (i < j) Og[(size_t)i * NN + j] = 0.f;
  }
  for (int k = j; k < NN; k++) {
    int src = k & 63;
    int reg = k >> 6;
    float bk;
    if (reg == 0) bk = __shfl(b0, src);
    else if (reg == 1) bk = __shfl(b1, src);
    else if (reg == 2) bk = __shfl(b2, src);
    else bk = __shfl(b3, src);
    float xk = bk * rdg[k];
    if (lane == 0) Og[(size_t)k * NN + j] = xk;
    const float* LTrow = LTg + (size_t)k * NN;
    int i0 = lane, i1 = lane + 64, i2 = lane + 128, i3 = lane + 192;
    if (i0 > k) b0 -= LTrow[i0] * xk;
    if (i1 > k) b1 -= LTrow[i1] * xk;
    if (i2 > k) b2 -= LTrow[i2] * xk;
    if (i3 > k) b3 -= LTrow[i3] * xk;
  }
}

// ---------------- K3: Kinv = Linv^T Linv (tiled SYRK-as-GEMM) ----------------
__global__ __launch_bounds__(256) void k_syrk(const float* __restrict__ Linv,
                                              float* __restrict__ Kinv) {
  int g = blockIdx.x >> 4;
  int tile = blockIdx.x & 15;
  int i0 = (tile >> 2) * 64, j0 = (tile & 3) * 64;
  const float* A = Linv + (size_t)g * NN * NN;
  float* O = Kinv + (size_t)g * NN * NN;
  __shared__ float sa[32][64], sb[32][64];
  int tx = threadIdx.x & 15, ty = threadIdx.x >> 4;
  float acc[4][4] = {{0.f}};
  for (int k0 = 0; k0 < NN; k0 += 32) {
    for (int e = threadIdx.x; e < 2048; e += 256) {
      int kk = e >> 6, cc = e & 63;
      sa[kk][cc] = A[(size_t)(k0 + kk) * NN + i0 + cc];
      sb[kk][cc] = A[(size_t)(k0 + kk) * NN + j0 + cc];
    }
    __syncthreads();
#pragma unroll 8
    for (int kk = 0; kk < 32; kk++) {
      float av[4], bv[4];
#pragma unroll
      for (int q = 0; q < 4; q++) { av[q] = sa[kk][ty * 4 + q]; bv[q] = sb[kk][tx * 4 + q]; }
#pragma unroll
      for (int q = 0; q < 4; q++)
#pragma unroll
        for (int r = 0; r < 4; r++) acc[q][r] += av[q] * bv[r];
    }
    __syncthreads();
  }
#pragma unroll
  for (int q = 0; q < 4; q++)
#pragma unroll
    for (int r = 0; r < 4; r++)
      O[(size_t)(i0 + ty * 4 + q) * NN + j0 + tx * 4 + r] = acc[q][r];
}

// ---------------- K-back: fused Q reduction (blocks 0..255) + mean/cross (256..263) ------
__global__ __launch_bounds__(256) void k_back(const float* __restrict__ u,
                                              const float* __restrict__ lkw,
                                              const float* __restrict__ Mw,
                                              const float* __restrict__ cvec,
                                              const float* __restrict__ Kinv,
                                              const float* __restrict__ y,
                                              const float* __restrict__ x,
                                              const float* __restrict__ mf,
                                              const float* __restrict__ cov,
                                              const float* __restrict__ scales,
                                              const float* __restrict__ Ainvw,
                                              const float* __restrict__ aimw,
                                              const float* __restrict__ mdcw,
                                              float* __restrict__ covp, float* __restrict__ trp,
                                              float* __restrict__ meanw, float* __restrict__ crossw) {
  int blk = blockIdx.x;
  int t = threadIdx.x;
  if (blk < 256) {
    int p = blk >> 2;
    int quarter = blk & 3;
    int a = p >> 3, b = p & 7;
    __shared__ __align__(16) float ub[NN * SA_DIM];
    __shared__ float Ms[100];
    __shared__ float sbv[NN];
    __shared__ __align__(16) float eb[NN];
    __shared__ __align__(16) float ysb[NN];
    __shared__ __align__(16) float ysa[NN];
    __shared__ float red[256];
    for (int idx = t; idx < NN * SA_DIM; idx += 256) ub[idx] = u[(size_t)b * NN * SA_DIM + idx];
    if (t < 100) Ms[t] = Mw[p * 100 + t];
    ysb[t] = y[t * S_DIM + b];
    ysa[t] = y[t * S_DIM + a];
    __syncthreads();
    {
      // beta_b[t] inline (Kinv symmetric: row t == col t)
      const float4* Kb = (const float4*)(Kinv + (size_t)b * NN * NN + (size_t)t * NN);
      float acc = 0.f;
      for (int m4 = 0; m4 < 64; m4++) {
        float4 kv = Kb[m4];
        float4 yv = ((const float4*)ysb)[m4];
        acc += kv.x * yv.x + kv.y * yv.y + kv.z * yv.z + kv.w * yv.w;
      }
      eb[t] = acc;
      int m = t;
      float q = 0.f;
#pragma unroll
      for (int d = 0; d < SA_DIM; d++) {
        float v = 0.f;
#pragma unroll
        for (int e = 0; e < SA_DIM; e++) v += Ms[d * SA_DIM + e] * ub[m * SA_DIM + e];
        q += v * ub[m * SA_DIM + d];
      }
      sbv[m] = lkw[b * NN + m] + 0.5f * q;
    }
    __syncthreads();
    int n = quarter * 64 + (t >> 2);
    int c = t & 3;
    float ua[SA_DIM];
#pragma unroll
    for (int d = 0; d < SA_DIM; d++) ua[d] = u[((size_t)a * NN + n) * SA_DIM + d];
    float va[SA_DIM];
#pragma unroll
    for (int d = 0; d < SA_DIM; d++) {
      float v = 0.f;
#pragma unroll
      for (int e = 0; e < SA_DIM; e++) v += Ms[d * SA_DIM + e] * ua[e];
      va[d] = v;
    }
    float qa = 0.f;
#pragma unroll
    for (int d = 0; d < SA_DIM; d++) qa += va[d] * ua[d];
    float pa = lkw[a * NN + n] + 0.5f * qa + cvec[p];
    float wa;
    if (a == b) {
      wa = eb[n];
    } else {
      const float4* Ka = (const float4*)(Kinv + (size_t)a * NN * NN + (size_t)n * NN);
      float acc = 0.f;
      for (int m4 = 0; m4 < 64; m4++) {
        float4 kv = Ka[m4];
        float4 yv = ((const float4*)ysa)[m4];
        acc += kv.x * yv.x + kv.y * yv.y + kv.z * yv.z + kv.w * yv.w;
      }
      wa = acc;
    }
    const float* Krow = Kinv + (size_t)a * NN * NN + (size_t)n * NN;
    float covacc = 0.f, tracc = 0.f;
    bool dg = (a == b);
    for (int ii = 0; ii < 64; ii++) {
      int mm = c + 4 * ii;
      float s = pa + sbv[mm];
#pragma unroll
      for (int d = 0; d < SA_DIM; d++) s += va[d] * ub[mm * SA_DIM + d];
      float e = __expf(s);
      covacc += eb[mm] * e;
      if (dg) tracc += Krow[mm] * e;
    }
    covacc *= wa;
    red[t] = covacc;
    __syncthreads();
    for (int st = 128; st > 0; st >>= 1) {
      if (t < st) red[t] += red[t + st];
      __syncthreads();
    }
    if (t == 0) covp[blk] = red[0];
    if (dg) {
      red[t] = tracc;
      __syncthreads();
      for (int st = 128; st > 0; st >>= 1) {
        if (t < st) red[t] += red[t + st];
        __syncthreads();
      }
      if (t == 0) trp[a * 4 + quarter] = red[0];
    }
  } else {
    int g = blk - 256;
    int i = t;
    __shared__ float Ai[100], cv[100], aims[SA_DIM], sc[SA_DIM], mfs[SA_DIM];
    __shared__ __align__(16) float ys[NN];
    __shared__ float red[256];
    if (i < 100) { Ai[i] = Ainvw[g * 100 + i]; cv[i] = cov[i]; }
    if (i < SA_DIM) { aims[i] = aimw[g * SA_DIM + i]; sc[i] = scales[g * SA_DIM + i]; mfs[i] = mf[i]; }
    ys[i] = y[i * S_DIM + g];
    __syncthreads();
    // beta_g[i] inline
    float bg;
    {
      const float4* Kg = (const float4*)(Kinv + (size_t)g * NN * NN + (size_t)i * NN);
      float acc = 0.f;
      for (int m4 = 0; m4 < 64; m4++) {
        float4 kv = Kg[m4];
        float4 yv = ((const float4*)ys)[m4];
        acc += kv.x * yv.x + kv.y * yv.y + kv.z * yv.z + kv.w * yv.w;
      }
      bg = acc;
    }
    float xi[SA_DIM], nu[SA_DIM];
#pragma unroll
    for (int d = 0; d < SA_DIM; d++) { xi[d] = x[i * SA_DIM + d]; nu[d] = xi[d] - mfs[d]; }
    float sv[SA_DIM], ad[SA_DIM];
#pragma unroll
    for (int d = 0; d < SA_DIM; d++) {
      float s1 = 0.f, s2 = 0.f;
#pragma unroll
      for (int e = 0; e < SA_DIM; e++) { s1 += Ai[d * SA_DIM + e] * nu[e]; s2 += Ai[d * SA_DIM + e] * xi[e]; }
      sv[d] = s1;
      ad[d] = s2;
    }
    float mq = 0.f;
#pragma unroll
    for (int d = 0; d < SA_DIM; d++) mq += nu[d] * sv[d];
    float mexp = mdcw[g] * __expf(-0.5f * mq);
    float cm = bg * mexp;
    float contrib[SA_DIM];
#pragma unroll
    for (int d = 0; d < SA_DIM; d++) {
      float ccm = sc[d] * aims[d];
#pragma unroll
      for (int j = 0; j < SA_DIM; j++) ccm += cv[d * SA_DIM + j] * ad[j];
      contrib[d] = mexp * ccm * bg;
    }
    red[i] = cm;
    __syncthreads();
    for (int st = 128; st > 0; st >>= 1) {
      if (i < st) red[i] += red[i + st];
      __syncthreads();
    }
    if (i == 0) meanw[g] = red[0];
    for (int d = 0; d < SA_DIM; d++) {
      __syncthreads();
      red[i] = contrib[d];
      __syncthreads();
      for (int st = 128; st > 0; st >>= 1) {
        if (i < st) red[i] += red[i + st];
        __syncthreads();
      }
      if (i == 0) crossw[d * S_DIM + g] = red[0];
    }
  }
}

// ---------------- K8: final assembly ----------------
__global__ __launch_bounds__(64) void k_final(const float* __restrict__ covp,
                                              const float* __restrict__ trp,
                                              const float* __restrict__ meanw,
                                              const float* __restrict__ crossw,
                                              const float* __restrict__ cov,
                                              const float* __restrict__ eqc,
                                              const float* __restrict__ mf,
                                              float* __restrict__ out) {
  int p = threadIdx.x;
  if (p >= 64) return;
  int a = p >> 3, b = p & 7;
  float covq = covp[p * 4] + covp[p * 4 + 1] + covp[p * 4 + 2] + covp[p * 4 + 3];
  float ma = meanw[a], mb = meanw[b];
  float val = covq - ma * mb + cov[a * SA_DIM + b];
  if (a == b) {
    float tr = trp[a * 4] + trp[a * 4 + 1] + trp[a * 4 + 2] + trp[a * 4 + 3];
    val += eqc[a] - tr;
  }
  val += (crossw[a * S_DIM + b] - mf[a] * mb) + (crossw[b * S_DIM + a] - mf[b] * ma);
  out[S_DIM + p] = val;
  if (p < S_DIM) out[p] = meanw[p] + mf[p];
}

extern "C" void kernel_launch(void* const* d_in, const int* in_sizes, int n_in,
                              void* d_out, int out_size, void* d_ws, size_t ws_size,
                              hipStream_t stream) {
  const float* mf     = (const float*)d_in[0];  // [10]
  const float* cov    = (const float*)d_in[1];  // [10,10]
  const float* x      = (const float*)d_in[2];  // [256,10]
  const float* y      = (const float*)d_in[3];  // [256,8]
  const float* eqc    = (const float*)d_in[4];  // [8]
  const float* scales = (const float*)d_in[5];  // [8,10]
  const float* noise  = (const float*)d_in[6];  // [8]
  float* ws = (float*)d_ws;

  float* Kw    = ws + OFF_K;     // K, then LT in place
  float* Linv  = ws + OFF_LINV;
  float* Kinv  = ws + OFF_KINV;
  float* rd    = ws + OFF_RD;
  float* u     = ws + OFF_U;
  float* lkw   = ws + OFF_LK;
  float* Mw    = ws + OFF_M;
  float* cvec  = ws + OFF_C;
  float* Ainvw = ws + OFF_AINV;
  float* aimw  = ws + OFF_AIM;
  float* mdcw  = ws + OFF_MDC;
  float* meanw = ws + OFF_MEAN;
  float* crossw= ws + OFF_CROSS;
  float* covp  = ws + OFF_COVP;
  float* trp   = ws + OFF_TRP;

  k_front<<<2057, 256, 0, stream>>>(x, mf, cov, eqc, scales, noise, Kw, u, lkw, Mw, cvec,
                                    Ainvw, aimw, mdcw);
  k_chol3<<<8, 1024, 0, stream>>>(Kw, rd);
  k_linv<<<512, 256, 0, stream>>>(Kw, rd, Linv);
  k_syrk<<<128, 256, 0, stream>>>(Linv, Kinv);
  k_back<<<264, 256, 0, stream>>>(u, lkw, Mw, cvec, Kinv, y, x, mf, cov, scales,
                                  Ainvw, aimw, mdcw, covp, trp, meanw, crossw);
  k_final<<<1, 64, 0, stream>>>(covp, trp, meanw, crossw, cov, eqc, mf, (float*)d_out);
}